// Round 10
// baseline (6720.909 us; speedup 1.0000x reference)
//
#include <hip/hip_runtime.h>

// CharRNN: 3-layer shared-weight LSTM (H=65) over T=4096, B=50, + dense head.
//
// Round-10: TLP + packed math on the R9 structure.
//   Block=1024 (16 waves, 4/SIMD, waves_per_eu(4,4) -> 128 VGPR cap).
//   Thread = (side, col-quad, 8-row window w=tid&7): C=4 cols x R=8 rows,
//   36 weight floats/thread. Staging = 2 ds_read_b128 + 1 broadcast b32 per
//   wave per layer. Dots via v_pk_fma_f32 (__builtin_elementwise_fma on
//   float2 ext_vector); 8-lane window reduction = 3 DPP adds
//   (quad xor1, quad xor2, row_half_mirror). Lane w==0 publishes 4 col dots.
//   R9 counters: VALU issue 1850 cyc of 3470 cyc/round at 2 waves/SIMD ->
//   ~1600 cyc stalls. 4 waves/SIMD + half per-wave work compress both.

#define HH    65
#define G4    260
#define TT    4096
#define NB    50
#define BLOCK 1024
#define DROWS 64

using v2f = __attribute__((ext_vector_type(2))) float;
#define PKFMA(a, b, c) __builtin_elementwise_fma((a), (b), (c))
#define KEEP(s) asm volatile("" : "+v"(s))

__device__ __forceinline__ float sigm(float x)  { return 1.0f / (1.0f + __expf(-x)); }
__device__ __forceinline__ float tanha(float x) { float e = __expf(2.0f * x); return 1.0f - 2.0f / (e + 1.0f); }

// sum across 8-lane group (lane bits 0-2): quad xor1, quad xor2, row_half_mirror
__device__ __forceinline__ float qsum8(float v) {
    int i = __float_as_int(v);
    v += __int_as_float(__builtin_amdgcn_update_dpp(0, i, 0xB1,  0xF, 0xF, true));
    i = __float_as_int(v);
    v += __int_as_float(__builtin_amdgcn_update_dpp(0, i, 0x4E,  0xF, 0xF, true));
    i = __float_as_int(v);
    v += __int_as_float(__builtin_amdgcn_update_dpp(0, i, 0x141, 0xF, 0xF, true));
    return v;
}

__global__ void __launch_bounds__(BLOCK)
__attribute__((amdgpu_waves_per_eu(4, 4)))
charrnn_rec(const float* __restrict__ x, const float* __restrict__ W,
            const float* __restrict__ U, const float* __restrict__ bv,
            float* __restrict__ out)
{
    __shared__ __align__(16) float s_hin[3][68];    // input to layer l (row0 = x(t)); [65..67]=0
    __shared__ __align__(16) float s_hrec[3][68];   // recurrent h per layer; [65..67]=0
    __shared__ __align__(16) float s_z[3][2][256];  // [layer][side][col] dots, cols 0..255
    __shared__ float s_parte[3][2][4];              // [layer][side][col-256] dots, cols 256..259

    const int bat  = blockIdx.x;
    const int tid  = threadIdx.x;
    const int lane = tid & 63;
    const int wv   = tid >> 6;
    const float* xb   = x   + (size_t)bat * TT * HH;
    float*       outb = out + (size_t)bat * TT * HH;

    for (int i = tid; i < 3 * 68; i += BLOCK) { (&s_hin[0][0])[i] = 0.0f; (&s_hrec[0][0])[i] = 0.0f; }

    const int w    = tid & 7;             // 8-row window: rows 8w..8w+7 (+row 64 on w==7)
    const int qC   = (tid >> 3) & 63;     // column quad within side
    const int col0 = qC * 4;              // cols col0..col0+3
    const int side = tid >> 9;            // 0 = W (reads hin), 1 = U (reads hrec)
    const float* M = side ? U : W;

    // 16 v2f weights (4 cols x 4 row-pairs) + 4 row-64 scalars (w==7 only)
    v2f wa0, wa1, wa2, wa3, wb0, wb1, wb2, wb3,
        wc0, wc1, wc2, wc3, wd0, wd1, wd2, wd3;
#define WLD(v, c, q)                                                          \
    do {                                                                      \
        float t0 = M[(8 * w + 2 * (q) + 0) * G4 + col0 + (c)];                \
        float t1 = M[(8 * w + 2 * (q) + 1) * G4 + col0 + (c)];                \
        KEEP(t0); KEEP(t1);                                                   \
        v = (v2f){t0, t1};                                                    \
    } while (0)
    WLD(wa0, 0, 0); WLD(wa1, 0, 1); WLD(wa2, 0, 2); WLD(wa3, 0, 3);
    WLD(wb0, 1, 0); WLD(wb1, 1, 1); WLD(wb2, 1, 2); WLD(wb3, 1, 3);
    WLD(wc0, 2, 0); WLD(wc1, 2, 1); WLD(wc2, 2, 2); WLD(wc3, 2, 3);
    WLD(wd0, 3, 0); WLD(wd1, 3, 1); WLD(wd2, 3, 2); WLD(wd3, 3, 3);
#undef WLD
    float ws0 = (w == 7) ? M[64 * G4 + col0 + 0] : 0.0f; KEEP(ws0);
    float ws1 = (w == 7) ? M[64 * G4 + col0 + 1] : 0.0f; KEEP(ws1);
    float ws2 = (w == 7) ? M[64 * G4 + col0 + 2] : 0.0f; KEEP(ws2);
    float ws3 = (w == 7) ? M[64 * G4 + col0 + 3] : 0.0f; KEEP(ws3);

    // extra cols 256..259: wave 0 (side 0) and wave 9 (side 1), lanes 0..31.
    // colX = 256 + (lane>>3); same staged h windows (w = lane&7).
    const bool isX  = ((wv == 0) || (wv == 9)) && (lane < 32);
    const int  colX = 256 + ((lane >> 3) & 3);
    v2f e0, e1, e2, e3;
#define ELD(v, q)                                                             \
    do {                                                                      \
        float t0 = isX ? M[(8 * w + 2 * (q) + 0) * G4 + colX] : 0.0f;         \
        float t1 = isX ? M[(8 * w + 2 * (q) + 1) * G4 + colX] : 0.0f;         \
        KEEP(t0); KEEP(t1);                                                   \
        v = (v2f){t0, t1};                                                    \
    } while (0)
    ELD(e0, 0); ELD(e1, 1); ELD(e2, 2); ELD(e3, 3);
#undef ELD
    float esc = (isX && w == 7) ? M[64 * G4 + colX] : 0.0f; KEEP(esc);

    // cell role (tid < 195): biases in registers
    const int  cl = tid / 65, n = tid - (tid / 65) * 65;
    const bool isC = (tid < 195);
    const float bz0 = bv[n], bz1 = bv[65 + n], bz2 = bv[130 + n], bz3 = bv[195 + n];
    float creg = 0.0f;

    // x prefetch: tids 959..1023 -> pidx 0..64
    const bool isP  = (tid >= 959);
    const int  pidx = tid - 959;
    float cur = 0.0f, nxt = 0.0f;
    if (isP) {
        s_hin[0][pidx] = xb[pidx];      // x(0)
        cur = xb[HH + pidx];            // x(1)
    }
    __syncthreads();

    for (int r = 0; r < TT + 2; ++r) {
        // ---------------- Phase A ----------------
        if (isP) {  // issue x(r+2) early; latency hidden under gate FMAs
            const int tn = r + 2;
            nxt = (tn < TT) ? xb[(size_t)tn * HH + pidx] : 0.0f;
        }
#pragma unroll
        for (int l = 0; l < 3; ++l) {
            if ((unsigned)(r - l) < TT) {
                const float* hb = side ? &s_hrec[l][0] : &s_hin[l][0];
                const float4* h4 = (const float4*)(hb + 8 * w);   // 16B aligned
                const float4 H0 = h4[0], H1 = h4[1];
                const float  h64 = hb[64];                         // broadcast b32
                const v2f hA = (v2f){H0.x, H0.y}, hB = (v2f){H0.z, H0.w};
                const v2f hC = (v2f){H1.x, H1.y}, hD = (v2f){H1.z, H1.w};
                float a0, a1, a2, a3;
#define CD(res, p0, p1, p2, p3, ps)                                           \
    {   v2f ac = hA * p0;                                                     \
        ac = PKFMA(hB, p1, ac);                                               \
        ac = PKFMA(hC, p2, ac);                                               \
        ac = PKFMA(hD, p3, ac);                                               \
        res = fmaf(h64, ps, ac.x + ac.y); }
                CD(a0, wa0, wa1, wa2, wa3, ws0)
                CD(a1, wb0, wb1, wb2, wb3, ws1)
                CD(a2, wc0, wc1, wc2, wc3, ws2)
                CD(a3, wd0, wd1, wd2, wd3, ws3)
                a0 = qsum8(a0); a1 = qsum8(a1); a2 = qsum8(a2); a3 = qsum8(a3);
                if ((lane & 7) == 0)
                    *(float4*)&s_z[l][side][col0] = make_float4(a0, a1, a2, a3);
                if (isX) {
                    float ea;
                    CD(ea, e0, e1, e2, e3, esc)
                    ea = qsum8(ea);
                    if ((lane & 7) == 0) s_parte[l][side][(lane >> 3) & 3] = ea;
                }
#undef CD
            }
        }
        __syncthreads();

        // ---------------- Phase B: cell updates ----------------
        if (isC) {
            if ((unsigned)(r - cl) < TT) {
                const float zi = bz0 + s_z[cl][0][n]       + s_z[cl][1][n];
                const float zf = bz1 + s_z[cl][0][65 + n]  + s_z[cl][1][65 + n];
                const float zg = bz2 + s_z[cl][0][130 + n] + s_z[cl][1][130 + n];
                float zo;
                if (n < 61) zo = bz3 + s_z[cl][0][195 + n]    + s_z[cl][1][195 + n];
                else        zo = bz3 + s_parte[cl][0][n - 61] + s_parte[cl][1][n - 61];
                const float ig = sigm(zi), fg = sigm(zf), gg = tanha(zg), og = sigm(zo);
                creg = fmaf(fg, creg, ig * gg);
                const float h = og * tanha(creg);
                s_hrec[cl][n] = h;
                if (cl < 2) s_hin[cl + 1][n] = h;
                else        outb[(size_t)(r - cl) * HH + n] = h;   // stream h2 to out
            }
        }
        if (isP) {
            if (r + 1 < TT) s_hin[0][pidx] = cur;
            cur = nxt;
        }
        __syncthreads();
    }
}

// ---- kernel 2: in-place dense head over d_out: y = h2 @ Wd + bd ----
__global__ void __launch_bounds__(256, 1)
dense_head(float* __restrict__ io, const float* __restrict__ Wd, const float* __restrict__ bd)
{
    __shared__ __align__(16) float s_h[DROWS][68];
    __shared__ float s_wd[HH][HH];
    __shared__ float s_bd[HH];

    const int tid = threadIdx.x;
    float* base = io + (size_t)blockIdx.x * DROWS * HH;

    for (int i = tid; i < DROWS * HH; i += 256) {
        const int row = i / HH, k = i - row * HH;
        s_h[row][k] = base[i];
    }
    for (int i = tid; i < HH * HH; i += 256) (&s_wd[0][0])[i] = Wd[i];
    if (tid < HH) s_bd[tid] = bd[tid];
    __syncthreads();

    for (int u = tid; u < DROWS * HH; u += 256) {
        const int row = u / HH, c = u - row * HH;
        const float4* hp = (const float4*)&s_h[row][0];
        float acc = s_bd[c];
#pragma unroll
        for (int k4 = 0; k4 < 16; ++k4) {
            const float4 hv = hp[k4];
            acc = fmaf(hv.x, s_wd[4 * k4 + 0][c], acc);
            acc = fmaf(hv.y, s_wd[4 * k4 + 1][c], acc);
            acc = fmaf(hv.z, s_wd[4 * k4 + 2][c], acc);
            acc = fmaf(hv.w, s_wd[4 * k4 + 3][c], acc);
        }
        acc = fmaf(s_h[row][64], s_wd[64][c], acc);
        base[u] = acc;   // safe: all reads come from LDS copies
    }
}

extern "C" void kernel_launch(void* const* d_in, const int* in_sizes, int n_in,
                              void* d_out, int out_size, void* d_ws, size_t ws_size,
                              hipStream_t stream)
{
    const float* x  = (const float*)d_in[0];
    const float* W  = (const float*)d_in[1];
    const float* U  = (const float*)d_in[2];
    const float* bv = (const float*)d_in[3];
    const float* Wd = (const float*)d_in[4];
    const float* bd = (const float*)d_in[5];
    float* out = (float*)d_out;

    hipLaunchKernelGGL(charrnn_rec, dim3(NB), dim3(BLOCK), 0, stream, x, W, U, bv, out);
    hipLaunchKernelGGL(dense_head, dim3(NB * TT / DROWS), dim3(256), 0, stream, out, Wd, bd);
}